// Round 2
// baseline (986.467 us; speedup 1.0000x reference)
//
#include <hip/hip_runtime.h>
#include <stdint.h>

// LocallyGroupedSelfAttention (B=512,N=200,C=512,NH=8,WS=5,HD=64).
// Dtype-robust: a sniff kernel detects fp32 vs packed-bf16 inputs at runtime;
// all math runs in bf16 MFMA either way; output written fp32 or bf16 per flag.
// Pipeline: sniff -> prep bias/weights(T) -> 4x [conv_x, qkv GEMM, window attn]
// -> proj GEMM. ws ~212 MB.

typedef unsigned short u16;
typedef __bf16 bf16_t;
typedef bf16_t bf16x8 __attribute__((ext_vector_type(8)));
typedef float f32x4 __attribute__((ext_vector_type(4)));
typedef u16 u16x8 __attribute__((ext_vector_type(8)));

__device__ __forceinline__ float b2f(u16 u) {
  return __uint_as_float(((uint32_t)u) << 16);
}
__device__ __forceinline__ u16 f2b(float f) {
  uint32_t u = __float_as_uint(f);
  u += 0x7FFFu + ((u >> 16) & 1u);  // RNE
  return (u16)(u >> 16);
}

// flag = 1 if x looks like fp32, 0 if packed bf16 pairs.
__global__ void k_sniff(const uint32_t* __restrict__ x,
                        uint32_t* __restrict__ flag) {
  if (threadIdx.x == 0 && blockIdx.x == 0) {
    int cnt = 0;
    for (int i = 0; i < 256; ++i) {
      uint32_t e = (x[i] >> 23) & 0xFFu;
      if (e >= 64u && e <= 192u) ++cnt;  // fp32 N(0,1) exponents land here
    }
    *flag = (cnt >= 128) ? 1u : 0u;
  }
}

__global__ void k_prep_bias(const void* __restrict__ qb,
                            const void* __restrict__ pb,
                            const uint32_t* __restrict__ flag,
                            u16* __restrict__ bq, u16* __restrict__ bp) {
  const bool f = (*flag) != 0;
  int i = blockIdx.x * 256 + threadIdx.x;
  if (i < 1536)
    bq[i] = f ? f2b(((const float*)qb)[i]) : ((const u16*)qb)[i];
  else {
    int j = i - 1536;
    if (j < 512) bp[j] = f ? f2b(((const float*)pb)[j]) : ((const u16*)pb)[j];
  }
}

// in[R][Cc] (fp32 or bf16 per flag) -> out[Cc][R] bf16. block (32,8).
__global__ void k_prep_w(const void* __restrict__ in, u16* __restrict__ out,
                         const uint32_t* __restrict__ flag, int R, int Cc) {
  __shared__ u16 tile[32][33];
  const bool f = (*flag) != 0;
  const int bx = blockIdx.x * 32, by = blockIdx.y * 32;
  const int tx = threadIdx.x, ty = threadIdx.y;
  for (int i = ty; i < 32; i += 8) {
    size_t idx = (size_t)(by + i) * Cc + bx + tx;
    tile[i][tx] = f ? f2b(((const float*)in)[idx]) : ((const u16*)in)[idx];
  }
  __syncthreads();
  for (int i = ty; i < 32; i += 8)
    out[(size_t)(bx + i) * R + by + tx] = tile[tx][i];
}

// fp32 -> bf16 chunk convert (no-op when inputs already bf16)
__global__ void k_conv_x(const float* __restrict__ x, u16* __restrict__ xb,
                         const uint32_t* __restrict__ flag, int n) {
  if ((*flag) == 0) return;
  int i = (blockIdx.x * 256 + threadIdx.x) * 8;
  if (i >= n) return;
  float4 a = *(const float4*)&x[i];
  float4 b = *(const float4*)&x[i + 4];
  u16x8 o;
  o[0] = f2b(a.x); o[1] = f2b(a.y); o[2] = f2b(a.z); o[3] = f2b(a.w);
  o[4] = f2b(b.x); o[5] = f2b(b.y); o[6] = f2b(b.z); o[7] = f2b(b.w);
  *(u16x8*)&xb[i] = o;
}

// ------------------------------------------------------------------- GEMM
// C[M][N] = A[M][K] @ Bt[N][K]^T + bias. 128x128 tile, BK=32, 4 waves 2x2.
// Register-staged (u16x8 load -> ds_write_b128); no global_load_lds this round.
#define BM 128
#define BN 128
#define BK 32

__global__ __launch_bounds__(256) void gemm_bt_bias(
    const u16* __restrict__ A0,  // A when flag==0 (bf16 world)
    const u16* __restrict__ A1,  // A when flag==1 (pre-converted bf16)
    const u16* __restrict__ Bt, const u16* __restrict__ bias,
    void* __restrict__ Cout, const uint32_t* __restrict__ flag,
    int N, int K, int out_f32_if_flag) {
  __shared__ u16 smem[BM * BN];  // 32 KB; staging in first 16 KB
  u16* As = smem;                // [BM][BK]
  u16* Bs = smem + BM * BK;      // [BN][BK]

  const bool f = (*flag) != 0;
  const u16* A = f ? A1 : A0;

  const int t = threadIdx.x;
  const int wave = t >> 6;
  const int lane = t & 63;
  const int waveM = wave & 1;
  const int waveN = wave >> 1;
  const int bm = blockIdx.y * BM;
  const int bn = blockIdx.x * BN;

  const int rowL = t >> 2;        // 0..63
  const int colL = (t & 3) * 8;   // 0,8,16,24
  const int kq = (lane >> 4) * 8;
  const int l15 = lane & 15;

  f32x4 acc[4][4] = {};

  for (int k0 = 0; k0 < K; k0 += BK) {
    u16x8 va0 = *(const u16x8*)&A[(size_t)(bm + rowL) * K + k0 + colL];
    u16x8 va1 = *(const u16x8*)&A[(size_t)(bm + rowL + 64) * K + k0 + colL];
    u16x8 vb0 = *(const u16x8*)&Bt[(size_t)(bn + rowL) * K + k0 + colL];
    u16x8 vb1 = *(const u16x8*)&Bt[(size_t)(bn + rowL + 64) * K + k0 + colL];
    __syncthreads();  // previous iter's LDS reads complete
    *(u16x8*)&As[rowL * BK + colL] = va0;
    *(u16x8*)&As[(rowL + 64) * BK + colL] = va1;
    *(u16x8*)&Bs[rowL * BK + colL] = vb0;
    *(u16x8*)&Bs[(rowL + 64) * BK + colL] = vb1;
    __syncthreads();

    bf16x8 af[4], bfr[4];
#pragma unroll
    for (int i = 0; i < 4; ++i)
      af[i] = *(const bf16x8*)&As[(waveM * 64 + i * 16 + l15) * BK + kq];
#pragma unroll
    for (int j = 0; j < 4; ++j)
      bfr[j] = *(const bf16x8*)&Bs[(waveN * 64 + j * 16 + l15) * BK + kq];
#pragma unroll
    for (int i = 0; i < 4; ++i)
#pragma unroll
      for (int j = 0; j < 4; ++j)
        acc[i][j] = __builtin_amdgcn_mfma_f32_16x16x32_bf16(af[i], bfr[j],
                                                            acc[i][j], 0, 0, 0);
  }

  float biasf[4];
#pragma unroll
  for (int j = 0; j < 4; ++j)
    biasf[j] = b2f(bias[bn + waveN * 64 + j * 16 + l15]);

  // C/D frag: col = lane&15, row = (lane>>4)*4 + reg  [m89/m91]
  if (out_f32_if_flag && f) {
    float* C = (float*)Cout;
#pragma unroll
    for (int i = 0; i < 4; ++i) {
      const int row0 = waveM * 64 + i * 16 + (lane >> 4) * 4;
#pragma unroll
      for (int j = 0; j < 4; ++j) {
        const int col = waveN * 64 + j * 16 + l15;
#pragma unroll
        for (int r = 0; r < 4; ++r)
          C[(size_t)(bm + row0 + r) * N + bn + col] = acc[i][j][r] + biasf[j];
      }
    }
  } else {
    u16* C = (u16*)Cout;
    __syncthreads();  // staging area now reusable for repack
#pragma unroll
    for (int i = 0; i < 4; ++i) {
      const int row0 = waveM * 64 + i * 16 + (lane >> 4) * 4;
#pragma unroll
      for (int j = 0; j < 4; ++j) {
        const int col = waveN * 64 + j * 16 + l15;
#pragma unroll
        for (int r = 0; r < 4; ++r)
          smem[(row0 + r) * BN + col] = f2b(acc[i][j][r] + biasf[j]);
      }
    }
    __syncthreads();
#pragma unroll
    for (int s = 0; s < 8; ++s) {
      const int vi = s * 256 + t;
      const int row = vi >> 4;
      const int col = (vi & 15) * 8;
      u16x8 v = *(const u16x8*)&smem[row * BN + col];
      *(u16x8*)&C[(size_t)(bm + row) * N + bn + col] = v;
    }
  }
}

// ------------------------------------------------------------- attention
// qkv[rows][1536]: Q [0,512), K [512,1024), V [1024,1536); head h at h*64.
// One wave per (window,head); lane = head dim.
__global__ __launch_bounds__(256) void attn_win(const u16* __restrict__ qkv,
                                                u16* __restrict__ o,
                                                int nwin) {
  const int wid = blockIdx.x * 4 + (threadIdx.x >> 6);
  const int lane = threadIdx.x & 63;
  const int h = wid & 7;
  const int w = wid >> 3;
  if (w >= nwin) return;
  const u16* base = qkv + (size_t)w * (5 * 1536) + h * 64 + lane;

  float q[5], k[5], v[5];
#pragma unroll
  for (int i = 0; i < 5; ++i) {
    q[i] = b2f(base[i * 1536]);
    k[i] = b2f(base[i * 1536 + 512]);
    v[i] = b2f(base[i * 1536 + 1024]);
  }
  float s[5][5];
#pragma unroll
  for (int i = 0; i < 5; ++i)
#pragma unroll
    for (int j = 0; j < 5; ++j) s[i][j] = q[i] * k[j];
#pragma unroll
  for (int off = 32; off > 0; off >>= 1) {
#pragma unroll
    for (int i = 0; i < 5; ++i)
#pragma unroll
      for (int j = 0; j < 5; ++j) s[i][j] += __shfl_xor(s[i][j], off, 64);
  }
  const float SCALE = 0.125f;  // 64^-0.5
  u16* ob = o + (size_t)w * (5 * 512) + h * 64 + lane;
#pragma unroll
  for (int i = 0; i < 5; ++i) {
    float m = s[i][0];
#pragma unroll
    for (int j = 1; j < 5; ++j) m = fmaxf(m, s[i][j]);
    float l = 0.f, acc = 0.f;
#pragma unroll
    for (int j = 0; j < 5; ++j) {
      float e = __expf((s[i][j] - m) * SCALE);
      l += e;
      acc += e * v[j];
    }
    ob[i * 512] = f2b(acc / l);
  }
}

// ---------------------------------------------------------------- launch
extern "C" void kernel_launch(void* const* d_in, const int* in_sizes, int n_in,
                              void* d_out, int out_size, void* d_ws,
                              size_t ws_size, hipStream_t stream) {
  const void* x      = d_in[0];  // [102400][512]  fp32 or bf16
  const void* qkv_w  = d_in[1];  // [512][1536]
  const void* qkv_b  = d_in[2];  // [1536]
  const void* proj_w = d_in[3];  // [512][512]
  const void* proj_b = d_in[4];  // [512]

  const int M = 102400, K = 512, N1 = 1536, N2 = 512;
  const int CH = 4, MC = M / CH;  // 25600 rows/chunk

  char* ws = (char*)d_ws;
  uint32_t* flag = (uint32_t*)ws;                       // @0
  u16* bq      = (u16*)(ws + 256);                      // 1536*2
  u16* bp      = (u16*)(ws + 256 + 3072);               // 512*2
  u16* wt_qkv  = (u16*)(ws + 8192);                     // 1536*512*2
  u16* wt_proj = (u16*)(ws + 8192 + 1572864);           // 512*512*2
  u16* attnb   = (u16*)(ws + 8192 + 1572864 + 524288);  // M*512*2 = 104.9 MB
  u16* qkvc    = (u16*)((char*)attnb + (size_t)M * 512 * 2);   // MC*1536*2
  u16* xbc     = (u16*)((char*)qkvc + (size_t)MC * 1536 * 2);  // MC*512*2
  // total ~212 MB

  k_sniff<<<1, 64, 0, stream>>>((const uint32_t*)x, flag);
  k_prep_bias<<<8, 256, 0, stream>>>(qkv_b, proj_b, flag, bq, bp);
  k_prep_w<<<dim3(N1 / 32, K / 32), dim3(32, 8), 0, stream>>>(qkv_w, wt_qkv,
                                                              flag, K, N1);
  k_prep_w<<<dim3(N2 / 32, K / 32), dim3(32, 8), 0, stream>>>(proj_w, wt_proj,
                                                              flag, K, N2);
  for (int c = 0; c < CH; ++c) {
    const size_t roff = (size_t)c * MC * 512;
    k_conv_x<<<MC * 512 / 2048, 256, 0, stream>>>((const float*)x + roff, xbc,
                                                  flag, MC * 512);
    gemm_bt_bias<<<dim3(N1 / BN, MC / BM), 256, 0, stream>>>(
        (const u16*)x + roff, xbc, wt_qkv, bq, qkvc, flag, N1, K, 0);
    attn_win<<<(MC / 5) * 8 / 4, 256, 0, stream>>>(qkvc, (u16*)attnb + roff,
                                                   MC / 5);
  }
  gemm_bt_bias<<<dim3(N2 / BN, M / BM), 256, 0, stream>>>(
      attnb, attnb, wt_proj, bp, d_out, flag, N2, K, 1);
}